// Round 7
// baseline (187.745 us; speedup 1.0000x reference)
//
#include <hip/hip_runtime.h>
#include <stdint.h>

#define IN_F 4096
#define OUT_F 4096

typedef __attribute__((ext_vector_type(4))) float f32x4;
typedef _Float16 f16x8 __attribute__((ext_vector_type(8)));
typedef _Float16 f16x2 __attribute__((ext_vector_type(2)));
typedef unsigned short u16x8 __attribute__((ext_vector_type(8)));

__device__ __forceinline__ unsigned short f2h(float f) {
  _Float16 h = (_Float16)f;
  return __builtin_bit_cast(unsigned short, h);
}

// k-permutation within each 8-group: position p holds original column sigma(p),
// sigma = [0,4,1,5,2,6,3,7]  (matches packed-f16 dequant output order)
#define SIGMA_TAB 0x73625140u

// ---------------- workspace layout (bytes) ----------------
#define OFF_XH     ((size_t)0)            // f16 x (col-permuted) [4096][4096]
#define OFF_PART   ((size_t)33554432)     // f32 partials[128][4096]
#define OFF_W      ((size_t)35651584)     // f32 w[4096]
#define OFF_BSUM   ((size_t)35667968)     // f32 bsum[16]
#define OFF_AW     ((size_t)35668480)     // f16 A_w[16][4096] (col-permuted)
#define OFF_BS     ((size_t)35799552)     // f16 Bs[4096][32]
#define OFF_HPART  ((size_t)36061696)     // f32 hpart[8][4096][16]
#define OFF_HB     ((size_t)38158848)     // f16 hb[4096][32]
#define WS_NEED    ((size_t)38420992)

// K1: x -> f16 (columns permuted within 8-groups) + per-column |x| partials
__global__ __launch_bounds__(256) void k1_prep(const float* __restrict__ x,
                                               unsigned short* __restrict__ xh,
                                               float* __restrict__ part) {
  int t = threadIdx.x;
  int c8 = (blockIdx.x * 256 + t) * 8;
  int by = blockIdx.y;
  float a[8];
  #pragma unroll
  for (int i = 0; i < 8; ++i) a[i] = 0.f;
  for (int rr = 0; rr < 32; ++rr) {
    size_t off = (size_t)(by * 32 + rr) * IN_F + c8;
    f32x4 v0 = *(const f32x4*)(x + off);
    f32x4 v1 = *(const f32x4*)(x + off + 4);
    u16x8 o;
    o[0] = f2h(v0[0]); o[1] = f2h(v1[0]); o[2] = f2h(v0[1]); o[3] = f2h(v1[1]);
    o[4] = f2h(v0[2]); o[5] = f2h(v1[2]); o[6] = f2h(v0[3]); o[7] = f2h(v1[3]);
    *(u16x8*)(xh + off) = o;
    a[0] += fabsf(v0[0]); a[1] += fabsf(v0[1]); a[2] += fabsf(v0[2]); a[3] += fabsf(v0[3]);
    a[4] += fabsf(v1[0]); a[5] += fabsf(v1[1]); a[6] += fabsf(v1[2]); a[7] += fabsf(v1[3]);
  }
  f32x4 p0 = { a[0], a[1], a[2], a[3] };
  f32x4 p1 = { a[4], a[5], a[6], a[7] };
  *(f32x4*)(part + (size_t)by * IN_F + c8) = p0;
  *(f32x4*)(part + (size_t)by * IN_F + c8 + 4) = p1;
}

// K2: reduce stripes -> w[col]; per-block sums of w
__global__ __launch_bounds__(256) void k2_colred(const float* __restrict__ part,
                                                 float* __restrict__ w,
                                                 float* __restrict__ bsum) {
  int t = threadIdx.x;
  int col = blockIdx.x * 256 + t;
  float s = 0.f;
  for (int st = 0; st < 128; ++st) s += part[(size_t)st * IN_F + col];
  float wv = s * (1.0f / 4096.0f);
  w[col] = wv;
  __shared__ float red[256];
  red[t] = wv; __syncthreads();
  for (int k = 128; k > 0; k >>= 1) { if (t < k) red[t] += red[t + k]; __syncthreads(); }
  if (t == 0) bsum[blockIdx.x] = red[0];
}

// K3: A_w (col-permuted, f16);  Bs[o][r] = 2*(B0+B1) padded to 32 (f16)
__global__ __launch_bounds__(256) void k3_fold(const float* __restrict__ lora_A,
                                               const float* __restrict__ lora_B,
                                               const float* __restrict__ w,
                                               const float* __restrict__ bsum,
                                               unsigned short* __restrict__ A_w,
                                               unsigned short* __restrict__ Bs) {
  int b = blockIdx.x, t = threadIdx.x;
  float s = 0.f;
  #pragma unroll
  for (int i = 0; i < 16; ++i) s += bsum[i];
  float iv = 1.0f / (s * (1.0f / 4096.0f) + 1e-6f);
  if (b < 256) {
    int idx = b * 256 + t;                 // [16][4096]
    int r = idx >> 12;
    int pos = idx & 4095;
    int p = pos & 7;
    int orig = (pos & ~7) + (int)((SIGMA_TAB >> (p * 4)) & 7);
    float v = (lora_A[(size_t)r * IN_F + orig] + lora_A[(size_t)(16 + r) * IN_F + orig]) * w[orig] * iv;
    A_w[idx] = f2h(v);
  } else {
    int idx = (b - 256) * 256 + t;         // [4096][32]
    int o = idx >> 5, r = idx & 31;
    float v = 0.f;
    if (r < 16) v = 2.0f * (lora_B[o * 16 + r] + lora_B[OUT_F * 16 + o * 16 + r]);
    Bs[idx] = f2h(v);
  }
}

// K4: hpart[kc][m][r] = sum_{k in chunk} xh[m][k]*A_w[r][k]  (f16 MFMA, K-split)
__global__ __launch_bounds__(256) void k4_h(const unsigned short* __restrict__ xh,
                                            const unsigned short* __restrict__ A_w,
                                            float* __restrict__ hpart) {
  int mb = blockIdx.x, kc = blockIdx.y;
  int t = threadIdx.x, wid = t >> 6, l = t & 63;
  int m0 = mb * 128 + wid * 32;
  int lr = l & 15, lg = l >> 4;
  f32x4 z = { 0.f, 0.f, 0.f, 0.f };
  f32x4 acc0 = z, acc1 = z;
  for (int it = 0; it < 16; ++it) {
    int k = kc * 512 + it * 32 + lg * 8;
    f16x8 b  = *(const f16x8*)(A_w + (size_t)lr * IN_F + k);
    f16x8 a0 = *(const f16x8*)(xh + (size_t)(m0 + lr) * IN_F + k);
    f16x8 a1 = *(const f16x8*)(xh + (size_t)(m0 + 16 + lr) * IN_F + k);
    acc0 = __builtin_amdgcn_mfma_f32_16x16x32_f16(a0, b, acc0, 0, 0, 0);
    acc1 = __builtin_amdgcn_mfma_f32_16x16x32_f16(a1, b, acc1, 0, 0, 0);
  }
  float* hp = hpart + (size_t)kc * IN_F * 16;
  #pragma unroll
  for (int r = 0; r < 4; ++r) {
    hp[(size_t)(m0 + lg * 4 + r) * 16 + lr]      = acc0[r];
    hp[(size_t)(m0 + 16 + lg * 4 + r) * 16 + lr] = acc1[r];
  }
}

// K5: reduce K-chunks -> hb[m][32] f16 (cols 16..31 zero)
__global__ __launch_bounds__(256) void k5_hred(const float* __restrict__ hpart,
                                               unsigned short* __restrict__ hb) {
  int gid = blockIdx.x * 256 + threadIdx.x;
  int m = gid >> 5, r = gid & 31;
  float v = 0.f;
  if (r < 16)
    for (int kc = 0; kc < 8; ++kc) v += hpart[(size_t)kc * 65536 + m * 16 + r];
  hb[gid] = f2h(v);
}

// packed f16 dequant: int32 (8 nibbles) -> f16x8 fragment, k-order [0,4,1,5,2,6,3,7]
__device__ __forceinline__ f16x8 deq8(unsigned int q, f16x2 s2, f16x2 zz2) {
  unsigned int u0 = ( q         & 0x000F000Fu) | 0x64006400u;
  unsigned int u1 = ((q >> 4)   & 0x000F000Fu) | 0x64006400u;
  unsigned int u2 = ((q >> 8)   & 0x000F000Fu) | 0x64006400u;
  unsigned int u3 = ((q >> 12)  & 0x000F000Fu) | 0x64006400u;
  f16x2 w0 = (__builtin_bit_cast(f16x2, u0) - zz2) * s2;
  f16x2 w1 = (__builtin_bit_cast(f16x2, u1) - zz2) * s2;
  f16x2 w2 = (__builtin_bit_cast(f16x2, u2) - zz2) * s2;
  f16x2 w3 = (__builtin_bit_cast(f16x2, u3) - zz2) * s2;
  struct { f16x2 a, b, c, d; } r { w0, w1, w2, w3 };
  return __builtin_bit_cast(f16x8, r);
}

// K6: out = xh * W + bias + hb*Bs^T.
// 128x128 tile, 4 waves (wave-tile 128x32), BK=128 (= GPTQ group): 32 K-tiles,
// one barrier pair per tile. A in LDS (2x32KB dbuf, FULL 4-bit XOR swizzle via
// pre-swizzled global source); B dequantized into registers; loop-carried ptrs.
// No setprio in the inner loop (scheduling fence -> serialized ds_read/MFMA; m190).
__global__ __launch_bounds__(256) void k6_gemm(const unsigned short* __restrict__ xh,
                                               const int* __restrict__ qweight,
                                               const int* __restrict__ qzeros,
                                               const float* __restrict__ scales,
                                               const float* __restrict__ bias,
                                               const unsigned short* __restrict__ hb,
                                               const unsigned short* __restrict__ Bs,
                                               float* __restrict__ out) {
  __shared__ __align__(16) unsigned short As[2][128 * 128];   // 2 x 32KB
  int t = threadIdx.x, w = t >> 6, l = t & 63;
  int lr = l & 15, lg = l >> 4;
  // XCD swizzle: 1024 blocks, 8 XCDs -> contiguous 128-chunk per XCD (bijective);
  // within a chunk 32 consecutive ids share mt -> A-panel L2-resident per XCD.
  int b0 = blockIdx.x;
  int bid = (b0 & 7) * 128 + (b0 >> 3);
  int mt = bid >> 5, nt = bid & 31;
  int m0 = mt * 128, n0 = nt * 128;
  int ncol0 = n0 + w * 32 + lr;            // this lane's n for j=0 (j adds 16)

  f32x4 zz = { 0.f, 0.f, 0.f, 0.f };
  f32x4 acc[8][2];
  #pragma unroll
  for (int m = 0; m < 8; ++m) { acc[m][0] = zz; acc[m][1] = zz; }

  // ---- loop-carried pointers (strides constant across kt) ----
  // stage: rows row0 + it*16; chunk c = t&15. Full 4-bit source swizzle:
  // physical chunk c of row r holds global chunk c ^ (r&15); (r&15)=row0 invariant.
  int row0 = t >> 4;
  int cp = (t & 15) ^ row0;                // kt-invariant 4-bit source swizzle
  const unsigned short* aE = xh + (size_t)(m0 + row0) * IN_F + cp * 8;  // tile 0
  const int*   qE = qweight + (size_t)lg * OUT_F + ncol0;               // tile 0
  const float* sE = scales + ncol0;                                     // group 0
  const int*   zE = qzeros + (ncol0 >> 3);                              // group 0
  int zsh = (lr & 7) * 4;                  // qzeros nibble shift (same for both j)

  #define STAGE_A(BUF, APTR) do {                                                 \
    _Pragma("unroll")                                                             \
    for (int it = 0; it < 8; ++it) {                                              \
      const unsigned short* gp = (APTR) + (size_t)it * 16 * IN_F;                 \
      __builtin_amdgcn_global_load_lds((const __attribute__((address_space(1))) void*)gp, \
                                       (__attribute__((address_space(3))) void*)(&As[BUF][0] + (it * 256 + t) * 8), \
                                       16, 0, 0);                                 \
    }                                                                             \
  } while (0)

  #define LOAD_QW(QW, QPTR) do {                                                  \
    _Pragma("unroll")                                                             \
    for (int ks = 0; ks < 4; ++ks)                                                \
      _Pragma("unroll")                                                           \
      for (int j = 0; j < 2; ++j)                                                 \
        QW[j][ks] = (unsigned int)(QPTR)[ks * 4 * OUT_F + j * 16];                \
  } while (0)

  #define LOAD_CONST(S2, ZP, SPTR, ZPTR) do {                                     \
    _Pragma("unroll")                                                             \
    for (int j = 0; j < 2; ++j) {                                                 \
      float s_ = (SPTR)[j * 16];                                                  \
      unsigned int zi = (unsigned int)(ZPTR)[j * 2];                              \
      unsigned int z = (zi >> zsh) & 0xFu;                                        \
      unsigned int zzu = 0x64006400u + z * 0x00010001u;                           \
      ZP[j] = __builtin_bit_cast(f16x2, zzu);                                     \
      _Float16 sh = (_Float16)s_;                                                 \
      unsigned int sb = (unsigned int)__builtin_bit_cast(unsigned short, sh);     \
      unsigned int ssu = (sb << 16) | sb;                                         \
      S2[j] = __builtin_bit_cast(f16x2, ssu);                                     \
    }                                                                             \
  } while (0)

  // read back: physical chunk = global chunk (ks*4+lg) XOR (row&15)=lr
  #define COMPUTE(BUF, QW, S2, ZP) do {                                           \
    _Pragma("unroll")                                                             \
    for (int ks = 0; ks < 4; ++ks) {                                              \
      f16x8 bf0 = deq8(QW[0][ks], S2[0], ZP[0]);                                  \
      f16x8 bf1 = deq8(QW[1][ks], S2[1], ZP[1]);                                  \
      f16x8 a[8];                                                                 \
      int chunk = (ks * 4 + lg) ^ lr;                                             \
      _Pragma("unroll")                                                           \
      for (int m = 0; m < 8; ++m)                                                 \
        a[m] = *(const f16x8*)(&As[BUF][0] + (m * 16 + lr) * 128 + chunk * 8);    \
      _Pragma("unroll")                                                           \
      for (int m = 0; m < 8; ++m) {                                               \
        acc[m][0] = __builtin_amdgcn_mfma_f32_16x16x32_f16(a[m], bf0, acc[m][0], 0, 0, 0); \
        acc[m][1] = __builtin_amdgcn_mfma_f32_16x16x32_f16(a[m], bf1, acc[m][1], 0, 0, 0); \
      }                                                                           \
    }                                                                             \
  } while (0)

  unsigned int qwA[2][4], qwB[2][4];
  f16x2 s2a[2], zpa[2], s2b[2], zpb[2];

  // prologue: tile 0 -> buf0/qwA/constsA
  STAGE_A(0, aE);
  LOAD_QW(qwA, qE);
  LOAD_CONST(s2a, zpa, sE, zE);
  // odd/even running pointers
  const unsigned short* aO = aE + 128;          // tile 1
  const int*   qO = qE + 16 * OUT_F;
  const float* sO = sE + OUT_F;
  const int*   zO = zE + OUT_F / 8;
  aE += 256; qE += 32 * OUT_F; sE += 2 * OUT_F; zE += 2 * (OUT_F / 8);  // tile 2
  __syncthreads();

  for (int kt = 0; kt < 32; kt += 2) {
    // phase E: prefetch tile kt+1 -> buf1/qwB/constsB, compute tile kt (buf0)
    LOAD_QW(qwB, qO);
    LOAD_CONST(s2b, zpb, sO, zO);
    STAGE_A(1, aO);
    COMPUTE(0, qwA, s2a, zpa);
    __syncthreads();
    // phase O: prefetch tile kt+2 -> buf0/qwA/constsA, compute tile kt+1 (buf1)
    if (kt + 2 < 32) {
      LOAD_QW(qwA, qE);
      LOAD_CONST(s2a, zpa, sE, zE);
      STAGE_A(0, aE);
    }
    COMPUTE(1, qwB, s2b, zpb);
    __syncthreads();
    aO += 256; qO += 32 * OUT_F; sO += 2 * OUT_F; zO += 2 * (OUT_F / 8);
    aE += 256; qE += 32 * OUT_F; sE += 2 * OUT_F; zE += 2 * (OUT_F / 8);
  }
  #undef STAGE_A
  #undef LOAD_QW
  #undef LOAD_CONST
  #undef COMPUTE

  // epilogue: rank-16 LoRA as one K=32 f16 MFMA per fragment
  {
    f16x8 bb[2];
    #pragma unroll
    for (int j = 0; j < 2; ++j)
      bb[j] = *(const f16x8*)(Bs + (size_t)(ncol0 + j * 16) * 32 + lg * 8);
    #pragma unroll
    for (int m = 0; m < 8; ++m) {
      f16x8 ah = *(const f16x8*)(hb + (size_t)(m0 + m * 16 + lr) * 32 + lg * 8);
      acc[m][0] = __builtin_amdgcn_mfma_f32_16x16x32_f16(ah, bb[0], acc[m][0], 0, 0, 0);
      acc[m][1] = __builtin_amdgcn_mfma_f32_16x16x32_f16(ah, bb[1], acc[m][1], 0, 0, 0);
    }
  }
  // bias + store
  #pragma unroll
  for (int j = 0; j < 2; ++j) {
    int ocol = ncol0 + j * 16;
    float bv = bias[ocol];
    #pragma unroll
    for (int m = 0; m < 8; ++m) {
      int orow = m0 + m * 16 + lg * 4;
      #pragma unroll
      for (int r = 0; r < 4; ++r)
        out[(size_t)(orow + r) * OUT_F + ocol] = acc[m][j][r] + bv;
    }
  }
}

extern "C" void kernel_launch(void* const* d_in, const int* in_sizes, int n_in,
                              void* d_out, int out_size, void* d_ws, size_t ws_size,
                              hipStream_t stream) {
  const float* x       = (const float*)d_in[0];
  const float* scales  = (const float*)d_in[1];
  const float* bias    = (const float*)d_in[2];
  const float* lora_A  = (const float*)d_in[3];
  const float* lora_B  = (const float*)d_in[4];
  const int*   qweight = (const int*)d_in[5];
  const int*   qzeros  = (const int*)d_in[6];
  float* out = (float*)d_out;

  if (ws_size < WS_NEED) return;

  char* ws = (char*)d_ws;
  unsigned short* xh  = (unsigned short*)(ws + OFF_XH);
  float* part         = (float*)(ws + OFF_PART);
  float* w            = (float*)(ws + OFF_W);
  float* bsum         = (float*)(ws + OFF_BSUM);
  unsigned short* A_w = (unsigned short*)(ws + OFF_AW);
  unsigned short* Bs  = (unsigned short*)(ws + OFF_BS);
  float* hpart        = (float*)(ws + OFF_HPART);
  unsigned short* hb  = (unsigned short*)(ws + OFF_HB);

  k1_prep<<<dim3(2, 128), 256, 0, stream>>>(x, xh, part);
  k2_colred<<<16, 256, 0, stream>>>(part, w, bsum);
  k3_fold<<<768, 256, 0, stream>>>(lora_A, lora_B, w, bsum, A_w, Bs);
  k4_h<<<dim3(32, 8), 256, 0, stream>>>(xh, A_w, hpart);
  k5_hred<<<512, 256, 0, stream>>>(hpart, hb);
  k6_gemm<<<1024, 256, 0, stream>>>(xh, qweight, qzeros, scales, bias, hb, Bs, out);
}

// Round 8
// 178.065 us; speedup vs baseline: 1.0544x; 1.0544x over previous
//
#include <hip/hip_runtime.h>
#include <stdint.h>

#define IN_F 4096
#define OUT_F 4096

typedef __attribute__((ext_vector_type(4))) float f32x4;
typedef _Float16 f16x8 __attribute__((ext_vector_type(8)));
typedef _Float16 f16x2 __attribute__((ext_vector_type(2)));
typedef unsigned short u16x8 __attribute__((ext_vector_type(8)));

__device__ __forceinline__ unsigned short f2h(float f) {
  _Float16 h = (_Float16)f;
  return __builtin_bit_cast(unsigned short, h);
}

// k-permutation within each 8-group: position p holds original column sigma(p),
// sigma = [0,4,1,5,2,6,3,7]  (matches packed-f16 dequant output order)
#define SIGMA_TAB 0x73625140u

// ---------------- workspace layout (bytes) ----------------
#define OFF_XH     ((size_t)0)            // f16 x (col-permuted) [4096][4096]
#define OFF_PART   ((size_t)33554432)     // f32 partials[128][4096]
#define OFF_W      ((size_t)35651584)     // f32 w[4096]
#define OFF_BSUM   ((size_t)35667968)     // f32 bsum[16]
#define OFF_AW     ((size_t)35668480)     // f16 A_w[16][4096] (col-permuted)
#define OFF_BS     ((size_t)35799552)     // f16 Bs[4096][32]
#define OFF_HPART  ((size_t)36061696)     // f32 hpart[8][4096][16]
#define OFF_HB     ((size_t)38158848)     // f16 hb[4096][32]
#define WS_NEED    ((size_t)38420992)

// K1: x -> f16 (columns permuted within 8-groups) + per-column |x| partials
__global__ __launch_bounds__(256) void k1_prep(const float* __restrict__ x,
                                               unsigned short* __restrict__ xh,
                                               float* __restrict__ part) {
  int t = threadIdx.x;
  int c8 = (blockIdx.x * 256 + t) * 8;
  int by = blockIdx.y;
  float a[8];
  #pragma unroll
  for (int i = 0; i < 8; ++i) a[i] = 0.f;
  for (int rr = 0; rr < 32; ++rr) {
    size_t off = (size_t)(by * 32 + rr) * IN_F + c8;
    f32x4 v0 = *(const f32x4*)(x + off);
    f32x4 v1 = *(const f32x4*)(x + off + 4);
    u16x8 o;
    o[0] = f2h(v0[0]); o[1] = f2h(v1[0]); o[2] = f2h(v0[1]); o[3] = f2h(v1[1]);
    o[4] = f2h(v0[2]); o[5] = f2h(v1[2]); o[6] = f2h(v0[3]); o[7] = f2h(v1[3]);
    *(u16x8*)(xh + off) = o;
    a[0] += fabsf(v0[0]); a[1] += fabsf(v0[1]); a[2] += fabsf(v0[2]); a[3] += fabsf(v0[3]);
    a[4] += fabsf(v1[0]); a[5] += fabsf(v1[1]); a[6] += fabsf(v1[2]); a[7] += fabsf(v1[3]);
  }
  f32x4 p0 = { a[0], a[1], a[2], a[3] };
  f32x4 p1 = { a[4], a[5], a[6], a[7] };
  *(f32x4*)(part + (size_t)by * IN_F + c8) = p0;
  *(f32x4*)(part + (size_t)by * IN_F + c8 + 4) = p1;
}

// K2: reduce stripes -> w[col]; per-block sums of w
__global__ __launch_bounds__(256) void k2_colred(const float* __restrict__ part,
                                                 float* __restrict__ w,
                                                 float* __restrict__ bsum) {
  int t = threadIdx.x;
  int col = blockIdx.x * 256 + t;
  float s = 0.f;
  for (int st = 0; st < 128; ++st) s += part[(size_t)st * IN_F + col];
  float wv = s * (1.0f / 4096.0f);
  w[col] = wv;
  __shared__ float red[256];
  red[t] = wv; __syncthreads();
  for (int k = 128; k > 0; k >>= 1) { if (t < k) red[t] += red[t + k]; __syncthreads(); }
  if (t == 0) bsum[blockIdx.x] = red[0];
}

// K3: A_w (col-permuted, f16);  Bs[o][r] = 2*(B0+B1) padded to 32 (f16)
__global__ __launch_bounds__(256) void k3_fold(const float* __restrict__ lora_A,
                                               const float* __restrict__ lora_B,
                                               const float* __restrict__ w,
                                               const float* __restrict__ bsum,
                                               unsigned short* __restrict__ A_w,
                                               unsigned short* __restrict__ Bs) {
  int b = blockIdx.x, t = threadIdx.x;
  float s = 0.f;
  #pragma unroll
  for (int i = 0; i < 16; ++i) s += bsum[i];
  float iv = 1.0f / (s * (1.0f / 4096.0f) + 1e-6f);
  if (b < 256) {
    int idx = b * 256 + t;                 // [16][4096]
    int r = idx >> 12;
    int pos = idx & 4095;
    int p = pos & 7;
    int orig = (pos & ~7) + (int)((SIGMA_TAB >> (p * 4)) & 7);
    float v = (lora_A[(size_t)r * IN_F + orig] + lora_A[(size_t)(16 + r) * IN_F + orig]) * w[orig] * iv;
    A_w[idx] = f2h(v);
  } else {
    int idx = (b - 256) * 256 + t;         // [4096][32]
    int o = idx >> 5, r = idx & 31;
    float v = 0.f;
    if (r < 16) v = 2.0f * (lora_B[o * 16 + r] + lora_B[OUT_F * 16 + o * 16 + r]);
    Bs[idx] = f2h(v);
  }
}

// K4: hpart[kc][m][r] = sum_{k in chunk} xh[m][k]*A_w[r][k]  (f16 MFMA, K-split)
__global__ __launch_bounds__(256) void k4_h(const unsigned short* __restrict__ xh,
                                            const unsigned short* __restrict__ A_w,
                                            float* __restrict__ hpart) {
  int mb = blockIdx.x, kc = blockIdx.y;
  int t = threadIdx.x, wid = t >> 6, l = t & 63;
  int m0 = mb * 128 + wid * 32;
  int lr = l & 15, lg = l >> 4;
  f32x4 z = { 0.f, 0.f, 0.f, 0.f };
  f32x4 acc0 = z, acc1 = z;
  for (int it = 0; it < 16; ++it) {
    int k = kc * 512 + it * 32 + lg * 8;
    f16x8 b  = *(const f16x8*)(A_w + (size_t)lr * IN_F + k);
    f16x8 a0 = *(const f16x8*)(xh + (size_t)(m0 + lr) * IN_F + k);
    f16x8 a1 = *(const f16x8*)(xh + (size_t)(m0 + 16 + lr) * IN_F + k);
    acc0 = __builtin_amdgcn_mfma_f32_16x16x32_f16(a0, b, acc0, 0, 0, 0);
    acc1 = __builtin_amdgcn_mfma_f32_16x16x32_f16(a1, b, acc1, 0, 0, 0);
  }
  float* hp = hpart + (size_t)kc * IN_F * 16;
  #pragma unroll
  for (int r = 0; r < 4; ++r) {
    hp[(size_t)(m0 + lg * 4 + r) * 16 + lr]      = acc0[r];
    hp[(size_t)(m0 + 16 + lg * 4 + r) * 16 + lr] = acc1[r];
  }
}

// K5: reduce K-chunks -> hb[m][32] f16 (cols 16..31 zero)
__global__ __launch_bounds__(256) void k5_hred(const float* __restrict__ hpart,
                                               unsigned short* __restrict__ hb) {
  int gid = blockIdx.x * 256 + threadIdx.x;
  int m = gid >> 5, r = gid & 31;
  float v = 0.f;
  if (r < 16)
    for (int kc = 0; kc < 8; ++kc) v += hpart[(size_t)kc * 65536 + m * 16 + r];
  hb[gid] = f2h(v);
}

// packed f16 dequant: int32 (8 nibbles) -> f16x8 fragment, k-order [0,4,1,5,2,6,3,7]
__device__ __forceinline__ f16x8 deq8(unsigned int q, f16x2 s2, f16x2 zz2) {
  unsigned int u0 = ( q         & 0x000F000Fu) | 0x64006400u;
  unsigned int u1 = ((q >> 4)   & 0x000F000Fu) | 0x64006400u;
  unsigned int u2 = ((q >> 8)   & 0x000F000Fu) | 0x64006400u;
  unsigned int u3 = ((q >> 12)  & 0x000F000Fu) | 0x64006400u;
  f16x2 w0 = (__builtin_bit_cast(f16x2, u0) - zz2) * s2;
  f16x2 w1 = (__builtin_bit_cast(f16x2, u1) - zz2) * s2;
  f16x2 w2 = (__builtin_bit_cast(f16x2, u2) - zz2) * s2;
  f16x2 w3 = (__builtin_bit_cast(f16x2, u3) - zz2) * s2;
  struct { f16x2 a, b, c, d; } r { w0, w1, w2, w3 };
  return __builtin_bit_cast(f16x8, r);
}

// K6: out = xh * W + bias + hb*Bs^T.
// 128x128 tile, 4 waves (wave-tile 128x32), BK=128 (= GPTQ group): 32 K-tiles,
// one barrier pair per tile. A in LDS (2x32KB dbuf, FULL 4-bit XOR swizzle via
// pre-swizzled global source -> 0 bank conflicts); B dequantized into registers;
// loop-carried pointers. setprio(1) around MFMA clusters (T5: 2 desynced
// blocks/CU give the arbiter a role-split; removal cost ~6% in round 7).
__global__ __launch_bounds__(256) void k6_gemm(const unsigned short* __restrict__ xh,
                                               const int* __restrict__ qweight,
                                               const int* __restrict__ qzeros,
                                               const float* __restrict__ scales,
                                               const float* __restrict__ bias,
                                               const unsigned short* __restrict__ hb,
                                               const unsigned short* __restrict__ Bs,
                                               float* __restrict__ out) {
  __shared__ __align__(16) unsigned short As[2][128 * 128];   // 2 x 32KB
  int t = threadIdx.x, w = t >> 6, l = t & 63;
  int lr = l & 15, lg = l >> 4;
  // XCD swizzle: 1024 blocks, 8 XCDs -> contiguous 128-chunk per XCD (bijective);
  // within a chunk 32 consecutive ids share mt -> A-panel L2-resident per XCD.
  int b0 = blockIdx.x;
  int bid = (b0 & 7) * 128 + (b0 >> 3);
  int mt = bid >> 5, nt = bid & 31;
  int m0 = mt * 128, n0 = nt * 128;
  int ncol0 = n0 + w * 32 + lr;            // this lane's n for j=0 (j adds 16)

  f32x4 zz = { 0.f, 0.f, 0.f, 0.f };
  f32x4 acc[8][2];
  #pragma unroll
  for (int m = 0; m < 8; ++m) { acc[m][0] = zz; acc[m][1] = zz; }

  // ---- loop-carried pointers (strides constant across kt) ----
  // stage: rows row0 + it*16; chunk c = t&15. Full 4-bit source swizzle:
  // physical chunk c of row r holds global chunk c ^ (r&15); (r&15)=row0 invariant.
  int row0 = t >> 4;
  int cp = (t & 15) ^ row0;                // kt-invariant 4-bit source swizzle
  const unsigned short* aE = xh + (size_t)(m0 + row0) * IN_F + cp * 8;  // tile 0
  const int*   qE = qweight + (size_t)lg * OUT_F + ncol0;               // tile 0
  const float* sE = scales + ncol0;                                     // group 0
  const int*   zE = qzeros + (ncol0 >> 3);                              // group 0
  int zsh = (lr & 7) * 4;                  // qzeros nibble shift (same for both j)

  #define STAGE_A(BUF, APTR) do {                                                 \
    _Pragma("unroll")                                                             \
    for (int it = 0; it < 8; ++it) {                                              \
      const unsigned short* gp = (APTR) + (size_t)it * 16 * IN_F;                 \
      __builtin_amdgcn_global_load_lds((const __attribute__((address_space(1))) void*)gp, \
                                       (__attribute__((address_space(3))) void*)(&As[BUF][0] + (it * 256 + t) * 8), \
                                       16, 0, 0);                                 \
    }                                                                             \
  } while (0)

  #define LOAD_QW(QW, QPTR) do {                                                  \
    _Pragma("unroll")                                                             \
    for (int ks = 0; ks < 4; ++ks)                                                \
      _Pragma("unroll")                                                           \
      for (int j = 0; j < 2; ++j)                                                 \
        QW[j][ks] = (unsigned int)(QPTR)[ks * 4 * OUT_F + j * 16];                \
  } while (0)

  #define LOAD_CONST(S2, ZP, SPTR, ZPTR) do {                                     \
    _Pragma("unroll")                                                             \
    for (int j = 0; j < 2; ++j) {                                                 \
      float s_ = (SPTR)[j * 16];                                                  \
      unsigned int zi = (unsigned int)(ZPTR)[j * 2];                              \
      unsigned int z = (zi >> zsh) & 0xFu;                                        \
      unsigned int zzu = 0x64006400u + z * 0x00010001u;                           \
      ZP[j] = __builtin_bit_cast(f16x2, zzu);                                     \
      _Float16 sh = (_Float16)s_;                                                 \
      unsigned int sb = (unsigned int)__builtin_bit_cast(unsigned short, sh);     \
      unsigned int ssu = (sb << 16) | sb;                                         \
      S2[j] = __builtin_bit_cast(f16x2, ssu);                                     \
    }                                                                             \
  } while (0)

  // read back: physical chunk = global chunk (ks*4+lg) XOR (row&15)=lr
  #define COMPUTE(BUF, QW, S2, ZP) do {                                           \
    _Pragma("unroll")                                                             \
    for (int ks = 0; ks < 4; ++ks) {                                              \
      f16x8 bf0 = deq8(QW[0][ks], S2[0], ZP[0]);                                  \
      f16x8 bf1 = deq8(QW[1][ks], S2[1], ZP[1]);                                  \
      f16x8 a[8];                                                                 \
      int chunk = (ks * 4 + lg) ^ lr;                                             \
      _Pragma("unroll")                                                           \
      for (int m = 0; m < 8; ++m)                                                 \
        a[m] = *(const f16x8*)(&As[BUF][0] + (m * 16 + lr) * 128 + chunk * 8);    \
      __builtin_amdgcn_s_setprio(1);                                              \
      _Pragma("unroll")                                                           \
      for (int m = 0; m < 8; ++m) {                                               \
        acc[m][0] = __builtin_amdgcn_mfma_f32_16x16x32_f16(a[m], bf0, acc[m][0], 0, 0, 0); \
        acc[m][1] = __builtin_amdgcn_mfma_f32_16x16x32_f16(a[m], bf1, acc[m][1], 0, 0, 0); \
      }                                                                           \
      __builtin_amdgcn_s_setprio(0);                                              \
    }                                                                             \
  } while (0)

  unsigned int qwA[2][4], qwB[2][4];
  f16x2 s2a[2], zpa[2], s2b[2], zpb[2];

  // prologue: tile 0 -> buf0/qwA/constsA
  STAGE_A(0, aE);
  LOAD_QW(qwA, qE);
  LOAD_CONST(s2a, zpa, sE, zE);
  // odd/even running pointers
  const unsigned short* aO = aE + 128;          // tile 1
  const int*   qO = qE + 16 * OUT_F;
  const float* sO = sE + OUT_F;
  const int*   zO = zE + OUT_F / 8;
  aE += 256; qE += 32 * OUT_F; sE += 2 * OUT_F; zE += 2 * (OUT_F / 8);  // tile 2
  __syncthreads();

  for (int kt = 0; kt < 32; kt += 2) {
    // phase E: prefetch tile kt+1 -> buf1/qwB/constsB, compute tile kt (buf0)
    LOAD_QW(qwB, qO);
    LOAD_CONST(s2b, zpb, sO, zO);
    STAGE_A(1, aO);
    COMPUTE(0, qwA, s2a, zpa);
    __syncthreads();
    // phase O: prefetch tile kt+2 -> buf0/qwA/constsA, compute tile kt+1 (buf1)
    if (kt + 2 < 32) {
      LOAD_QW(qwA, qE);
      LOAD_CONST(s2a, zpa, sE, zE);
      STAGE_A(0, aE);
    }
    COMPUTE(1, qwB, s2b, zpb);
    __syncthreads();
    aO += 256; qO += 32 * OUT_F; sO += 2 * OUT_F; zO += 2 * (OUT_F / 8);
    aE += 256; qE += 32 * OUT_F; sE += 2 * OUT_F; zE += 2 * (OUT_F / 8);
  }
  #undef STAGE_A
  #undef LOAD_QW
  #undef LOAD_CONST
  #undef COMPUTE

  // epilogue: rank-16 LoRA as one K=32 f16 MFMA per fragment
  {
    f16x8 bb[2];
    #pragma unroll
    for (int j = 0; j < 2; ++j)
      bb[j] = *(const f16x8*)(Bs + (size_t)(ncol0 + j * 16) * 32 + lg * 8);
    #pragma unroll
    for (int m = 0; m < 8; ++m) {
      f16x8 ah = *(const f16x8*)(hb + (size_t)(m0 + m * 16 + lr) * 32 + lg * 8);
      acc[m][0] = __builtin_amdgcn_mfma_f32_16x16x32_f16(ah, bb[0], acc[m][0], 0, 0, 0);
      acc[m][1] = __builtin_amdgcn_mfma_f32_16x16x32_f16(ah, bb[1], acc[m][1], 0, 0, 0);
    }
  }
  // bias + store
  #pragma unroll
  for (int j = 0; j < 2; ++j) {
    int ocol = ncol0 + j * 16;
    float bv = bias[ocol];
    #pragma unroll
    for (int m = 0; m < 8; ++m) {
      int orow = m0 + m * 16 + lg * 4;
      #pragma unroll
      for (int r = 0; r < 4; ++r)
        out[(size_t)(orow + r) * OUT_F + ocol] = acc[m][j][r] + bv;
    }
  }
}

extern "C" void kernel_launch(void* const* d_in, const int* in_sizes, int n_in,
                              void* d_out, int out_size, void* d_ws, size_t ws_size,
                              hipStream_t stream) {
  const float* x       = (const float*)d_in[0];
  const float* scales  = (const float*)d_in[1];
  const float* bias    = (const float*)d_in[2];
  const float* lora_A  = (const float*)d_in[3];
  const float* lora_B  = (const float*)d_in[4];
  const int*   qweight = (const int*)d_in[5];
  const int*   qzeros  = (const int*)d_in[6];
  float* out = (float*)d_out;

  if (ws_size < WS_NEED) return;

  char* ws = (char*)d_ws;
  unsigned short* xh  = (unsigned short*)(ws + OFF_XH);
  float* part         = (float*)(ws + OFF_PART);
  float* w            = (float*)(ws + OFF_W);
  float* bsum         = (float*)(ws + OFF_BSUM);
  unsigned short* A_w = (unsigned short*)(ws + OFF_AW);
  unsigned short* Bs  = (unsigned short*)(ws + OFF_BS);
  float* hpart        = (float*)(ws + OFF_HPART);
  unsigned short* hb  = (unsigned short*)(ws + OFF_HB);

  k1_prep<<<dim3(2, 128), 256, 0, stream>>>(x, xh, part);
  k2_colred<<<16, 256, 0, stream>>>(part, w, bsum);
  k3_fold<<<768, 256, 0, stream>>>(lora_A, lora_B, w, bsum, A_w, Bs);
  k4_h<<<dim3(32, 8), 256, 0, stream>>>(xh, A_w, hpart);
  k5_hred<<<512, 256, 0, stream>>>(hpart, hb);
  k6_gemm<<<1024, 256, 0, stream>>>(xh, qweight, qzeros, scales, bias, hb, Bs, out);
}